// Round 9
// baseline (87.287 us; speedup 1.0000x reference)
//
#include <hip/hip_runtime.h>
#include <math.h>

// Problem constants (fixed by setup_inputs): N src points, M targets, D=3.
constexpr int N_SRC = 16384;
constexpr int M_TAR = 16384;

// R14: attack the remaining 2.8x gap (nn ~35us vs 12.7us issue floor, with
// barriers already deleted) on three fronts:
//  (1) Coefficients via PROVABLY-UNIFORM loads -> s_load_dwordx16, killing
//      the readfirstlane machinery (R12/R13 reported SGPR_Count=48 < the 48
//      coefficients -- they were living somewhere costly). Switch to the
//      max-form u = t.s - ||s||^2/2: prep stores -0.5*||s||^2, so the raw
//      tar values are the coefficients (no -2 scaling -> no scalar-float
//      math). u = -v/2 BIT-EXACTLY (x2^k commutes with fma rounding), so
//      the winner is identical to all previous rounds.
//  (2) Full-machine TLP: TPB=1024, grid 512 -> 8192 waves (was 4096).
//      32 rows/thread, tail LDS 64 KB -> 2 blocks/CU.
//  (3) Depth-2 register pipeline (4 loads in flight, use-distance ~2
//      comps) + unroll 2 so rotation renames instead of v_mov.
// Per source-pair: 6 v_fma_f32 + 1 v_max3_f32 = 3.5 VALU ops/pair.
constexpr int BLOCKS = 512;            // 32 targets per block
constexpr int TPB = 1024;              // 16 waves
constexpr int CHUNKS = 512;            // chunk = tid & 511
constexpr int TPT = 16;                // targets per wave-half
constexpr int NROWS = N_SRC / CHUNKS;  // 32 rows per chunk

__global__ void prep(const float* __restrict__ src,
                     float4* __restrict__ ws,
                     float* __restrict__ out) {
    int i = blockIdx.x * blockDim.x + threadIdx.x;   // 16384 threads exact
    if (i == 0) out[0] = 0.0f;  // d_out poisoned 0xAA each launch
    const float* q = src + 3 * i;
    float x = q[0], y = q[1], z = q[2];
    // exact op order matters: nn15's rescan replicates this bit-for-bit
    ws[i] = make_float4(x, y, z, -0.5f * fmaf(x, x, fmaf(y, y, z * z)));
}

// best = max(best, e0, e1) in one instruction (inputs never NaN here)
__device__ __forceinline__ void max3(float& b, float e0, float e1) {
    asm("v_max3_f32 %0, %0, %1, %2"
        : "+v"(b) : "v"(e0), "v"(e1));
}

__global__ __launch_bounds__(TPB, 2)
void nn15(const float4* __restrict__ ws,
          const float* __restrict__ src,
          const float* __restrict__ tar,
          float* __restrict__ out) {
    __shared__ float fv[32 * CHUNKS];  // 64 KB, tail reduction only

    const int tid   = threadIdx.x;
    const int g     = tid >> 9;     // 0..1: wave-uniform target half
    const int chunk = tid & 511;    // 0..511: source slice
    const int tbase = blockIdx.x * 32;

    // Wave-uniform target pointer: readfirstlane the INDEX, so the 48
    // coefficient loads have a provably uniform address -> s_load.
    const int gu = __builtin_amdgcn_readfirstlane(g);
    const float* tw = tar + 3 * (tbase + gu * TPT);
    float tx[TPT], ty[TPT], tz[TPT], best[TPT];
#pragma unroll
    for (int k = 0; k < TPT; ++k) {
        tx[k] = tw[3 * k + 0];
        ty[k] = tw[3 * k + 1];
        tz[k] = tw[3 * k + 2];
        best[k] = -INFINITY;       // tracking MAX of u = t.s - ||s||^2/2
    }

    auto comp = [&](float4 s0, float4 s1) {
#pragma unroll
        for (int k = 0; k < TPT; ++k) {
            float t0 = fmaf(s0.z, tz[k], s0.w);   // 1 SGPR operand each
            t0 = fmaf(s0.y, ty[k], t0);
            t0 = fmaf(s0.x, tx[k], t0);
            float t1 = fmaf(s1.z, tz[k], s1.w);
            t1 = fmaf(s1.y, ty[k], t1);
            t1 = fmaf(s1.x, tx[k], t1);
            max3(best[k], t0, t1);   // 7 VALU per 2 pairs = 3.5/pair
        }
    };

    // ---- barrier-free main loop: depth-2 register pipeline over 32 rows
    float4 s0 = ws[0 * CHUNKS + chunk];
    float4 s1 = ws[1 * CHUNKS + chunk];
    float4 n0 = ws[2 * CHUNKS + chunk];
    float4 n1 = ws[3 * CHUNKS + chunk];
#pragma unroll 2
    for (int r = 0; r + 4 < NROWS; r += 2) {
        float4 f0 = ws[(r + 4) * CHUNKS + chunk];
        float4 f1 = ws[(r + 5) * CHUNKS + chunk];
        __builtin_amdgcn_sched_barrier(0);  // loads issue above the compute
        comp(s0, s1);
        s0 = n0; s1 = n1; n0 = f0; n1 = f1;  // renamed by unroll 2
    }
    comp(s0, s1);   // rows 28,29
    comp(n0, n1);   // rows 30,31

    // ---- tail: per-target reduce (value, chunk), then rescan winning chunk
#pragma unroll
    for (int k = 0; k < TPT; ++k) {
        fv[(g * TPT + k) * CHUNKS + chunk] = best[k];
    }
    __syncthreads();

    const int tprime = tid >> 5;   // 0..31: target this 32-lane group reduces
    const int sub    = tid & 31;
    float bv = fv[tprime * CHUNKS + sub];
    int   bc = sub;                // winning chunk id
#pragma unroll
    for (int m = 1; m < CHUNKS / 32; ++m) {
        float v = fv[tprime * CHUNKS + sub + 32 * m];
        if (v > bv) { bv = v; bc = sub + 32 * m; }
    }
#pragma unroll
    for (int s = 16; s >= 1; s >>= 1) {  // xor<32 stays in the aligned group
        float vv = __shfl_xor(bv, s, 64);
        int   cc = __shfl_xor(bc, s, 64);
        if (vv > bv) { bv = vv; bc = cc; }
    }
    // all 32 lanes of the group now hold (bv, bc) for target tprime.

    // ---- rescan: find the row in chunk bc whose value bit-matches bv.
    // Same fma chain as pass 1 (and prep) -> winning row reproduces bv.
    const int T = tbase + tprime;
    const float qx = tar[3 * T + 0], qy = tar[3 * T + 1], qz = tar[3 * T + 2];
    int myrow;
    {
        int j = sub * CHUNKS + bc;       // row = sub (0..31), one row/lane
        const float* q = src + 3 * j;
        float x = q[0], y = q[1], z = q[2];
        float h = -0.5f * fmaf(x, x, fmaf(y, y, z * z));
        float v = fmaf(z, qz, h);
        v = fmaf(y, qy, v);
        v = fmaf(x, qx, v);
        myrow = (v == bv) ? sub : NROWS;
    }
#pragma unroll
    for (int s = 16; s >= 1; s >>= 1) {
        int r2 = __shfl_xor(myrow, s, 64);
        if (r2 < myrow) myrow = r2;
    }
    __syncthreads();  // done reading fv; safe to overwrite fv[0..31]

    if (sub == 0) {
        int j = myrow * CHUNKS + bc;
        // exact loss term from the winning index (reference formula)
        float dx = src[3 * j + 0] - qx;
        float dy = src[3 * j + 1] - qy;
        float dz = src[3 * j + 2] - qz;
        fv[tprime] = 0.5f * fmaf(dx, dx, fmaf(dy, dy, dz * dz));
    }
    __syncthreads();
    if (tid == 0) {
        float ssum = 0.0f;
#pragma unroll
        for (int i = 0; i < 32; ++i) ssum += fv[i];
        atomicAdd(out, ssum);  // device-scope, cross-XCD safe
    }
}

extern "C" void kernel_launch(void* const* d_in, const int* in_sizes, int n_in,
                              void* d_out, int out_size, void* d_ws, size_t ws_size,
                              hipStream_t stream) {
    const float* src = (const float*)d_in[0];  // src_V [N,3] fp32
    const float* tar = (const float*)d_in[1];  // tar_V [M,3] fp32
    float* out = (float*)d_out;                // scalar loss fp32
    float4* ws = (float4*)d_ws;                // 256 KB: (x,y,z,-||s||^2/2)
    (void)ws_size;

    prep<<<N_SRC / 512, 512, 0, stream>>>(src, ws, out);
    nn15<<<BLOCKS, TPB, 0, stream>>>(ws, src, tar, out);
}

// Round 10
// 85.076 us; speedup vs baseline: 1.0260x; 1.0260x over previous
//
#include <hip/hip_runtime.h>
#include <math.h>

// Problem constants (fixed by setup_inputs): N src points, M targets, D=3.
constexpr int N_SRC = 16384;
constexpr int M_TAR = 16384;

// R15: clock-corrected model. Busy-time (VALUBusy x dur) across R7-R12
// tracks the instruction stream exactly (4.5ops+shuffles -> 30.7us;
// 3.5ops -> 25-27us), implying effective core clock ~1.15 GHz in this
// timed region (short kernels + graph replay never ramp DVFS; the 40us
// 256MiB fills are memory-bound). At 1.15 GHz the 3.5-op stream's issue
// floor IS ~25us: we are AT the floor in busy-time. Remaining slack =
// duration-busy gap (~10-13us of stalls/tail). This round attacks that:
//  (1) 1024 blocks x 512 threads, 16 targets/block: halves block runtime
//      (shorter tail), 4 blocks/CU x 8 waves = full 2048-thread residency.
//  (2) depth-3 register pipeline (6 float4 in flight, use-distance ~2
//      comp-blocks) -- covers L2 latency at any clock.
//  (3) __launch_bounds__(512,4): the <=64-VGPR tier (R7-verified); live
//      set ~55 VGPR now fits (coefs live in SGPRs via uniform s_load).
// Per source-pair: 3 v_fma_f32 + 0.5 v_max3_f32 = 3.5 VALU ops/pair,
// max-form u = t.s - ||s||^2/2 (bit-commutes with the min-form by x2^k).
constexpr int BLOCKS = M_TAR / 16;     // 1024; 16 targets per block
constexpr int TPB = 512;               // 8 waves
constexpr int CHUNKS = 512;            // chunk = tid & 511
constexpr int TPT = 16;                // all threads share the block's 16
constexpr int NROWS = N_SRC / CHUNKS;  // 32 rows per chunk

__global__ void prep(const float* __restrict__ src,
                     float4* __restrict__ ws,
                     float* __restrict__ out) {
    int i = blockIdx.x * blockDim.x + threadIdx.x;   // 16384 threads exact
    if (i == 0) out[0] = 0.0f;  // d_out poisoned 0xAA each launch
    const float* q = src + 3 * i;
    float x = q[0], y = q[1], z = q[2];
    // exact op order matters: nn16's rescan replicates this bit-for-bit
    ws[i] = make_float4(x, y, z, -0.5f * fmaf(x, x, fmaf(y, y, z * z)));
}

// best = max(best, e0, e1) in one instruction (inputs never NaN here)
__device__ __forceinline__ void max3(float& b, float e0, float e1) {
    asm("v_max3_f32 %0, %0, %1, %2"
        : "+v"(b) : "v"(e0), "v"(e1));
}

__global__ __launch_bounds__(TPB, 4)
void nn16(const float4* __restrict__ ws,
          const float* __restrict__ src,
          const float* __restrict__ tar,
          float* __restrict__ out) {
    __shared__ float fv[TPT * CHUNKS];  // 32 KB, tail reduction only

    const int tid   = threadIdx.x;
    const int chunk = tid & 511;    // 0..511: source slice
    const int tbase = blockIdx.x * TPT;

    // Block-uniform target pointer -> the 48 coefficient loads are
    // provably uniform -> s_load into SGPRs. No per-lane copies.
    const float* tw = tar + 3 * tbase;
    float tx[TPT], ty[TPT], tz[TPT], best[TPT];
#pragma unroll
    for (int k = 0; k < TPT; ++k) {
        tx[k] = tw[3 * k + 0];
        ty[k] = tw[3 * k + 1];
        tz[k] = tw[3 * k + 2];
        best[k] = -INFINITY;       // tracking MAX of u = t.s - ||s||^2/2
    }

    auto comp = [&](float4 s0, float4 s1) {
#pragma unroll
        for (int k = 0; k < TPT; ++k) {
            float t0 = fmaf(s0.z, tz[k], s0.w);   // 1 SGPR operand each
            t0 = fmaf(s0.y, ty[k], t0);
            t0 = fmaf(s0.x, tx[k], t0);
            float t1 = fmaf(s1.z, tz[k], s1.w);
            t1 = fmaf(s1.y, ty[k], t1);
            t1 = fmaf(s1.x, tx[k], t1);
            max3(best[k], t0, t1);   // 7 VALU per 2 pairs = 3.5/pair
        }
    };

    // ---- barrier-free main loop: depth-3 register pipeline over 32 rows
    float4 s0 = ws[0 * CHUNKS + chunk], s1 = ws[1 * CHUNKS + chunk];
    float4 n0 = ws[2 * CHUNKS + chunk], n1 = ws[3 * CHUNKS + chunk];
    float4 m0 = ws[4 * CHUNKS + chunk], m1 = ws[5 * CHUNKS + chunk];
#pragma unroll
    for (int r = 0; r + 6 < NROWS; r += 2) {
        float4 f0 = ws[(r + 6) * CHUNKS + chunk];
        float4 f1 = ws[(r + 7) * CHUNKS + chunk];
        __builtin_amdgcn_sched_barrier(0);  // loads issue above the compute
        comp(s0, s1);
        s0 = n0; s1 = n1; n0 = m0; n1 = m1; m0 = f0; m1 = f1;
    }
    comp(s0, s1);   // rows 26,27
    comp(n0, n1);   // rows 28,29
    comp(m0, m1);   // rows 30,31

    // ---- tail: per-target reduce (value, chunk), then rescan winning chunk
#pragma unroll
    for (int k = 0; k < TPT; ++k) {
        fv[k * CHUNKS + chunk] = best[k];
    }
    __syncthreads();

    const int tprime = tid >> 5;   // 0..15: target this 32-lane group reduces
    const int sub    = tid & 31;
    float bv = fv[tprime * CHUNKS + sub];
    int   bc = sub;                // winning chunk id
#pragma unroll
    for (int m = 1; m < CHUNKS / 32; ++m) {
        float v = fv[tprime * CHUNKS + sub + 32 * m];
        if (v > bv) { bv = v; bc = sub + 32 * m; }
    }
#pragma unroll
    for (int s = 16; s >= 1; s >>= 1) {  // xor<32 stays in the aligned group
        float vv = __shfl_xor(bv, s, 64);
        int   cc = __shfl_xor(bc, s, 64);
        if (vv > bv) { bv = vv; bc = cc; }
    }
    // all 32 lanes of the group now hold (bv, bc) for target tprime.

    // ---- rescan: find the row in chunk bc whose value bit-matches bv.
    // Same fma chain as pass 1 (and prep) -> winning row reproduces bv.
    const int T = tbase + tprime;
    const float qx = tar[3 * T + 0], qy = tar[3 * T + 1], qz = tar[3 * T + 2];
    int myrow;
    {
        int j = sub * CHUNKS + bc;       // row = sub (0..31), one row/lane
        const float* q = src + 3 * j;
        float x = q[0], y = q[1], z = q[2];
        float h = -0.5f * fmaf(x, x, fmaf(y, y, z * z));
        float v = fmaf(z, qz, h);
        v = fmaf(y, qy, v);
        v = fmaf(x, qx, v);
        myrow = (v == bv) ? sub : NROWS;
    }
#pragma unroll
    for (int s = 16; s >= 1; s >>= 1) {
        int r2 = __shfl_xor(myrow, s, 64);
        if (r2 < myrow) myrow = r2;
    }
    __syncthreads();  // done reading fv; safe to overwrite fv[0..15]

    if (sub == 0) {
        int j = myrow * CHUNKS + bc;
        // exact loss term from the winning index (reference formula)
        float dx = src[3 * j + 0] - qx;
        float dy = src[3 * j + 1] - qy;
        float dz = src[3 * j + 2] - qz;
        fv[tprime] = 0.5f * fmaf(dx, dx, fmaf(dy, dy, dz * dz));
    }
    __syncthreads();
    if (tid == 0) {
        float ssum = 0.0f;
#pragma unroll
        for (int i = 0; i < TPT; ++i) ssum += fv[i];
        atomicAdd(out, ssum);  // device-scope, cross-XCD safe
    }
}

extern "C" void kernel_launch(void* const* d_in, const int* in_sizes, int n_in,
                              void* d_out, int out_size, void* d_ws, size_t ws_size,
                              hipStream_t stream) {
    const float* src = (const float*)d_in[0];  // src_V [N,3] fp32
    const float* tar = (const float*)d_in[1];  // tar_V [M,3] fp32
    float* out = (float*)d_out;                // scalar loss fp32
    float4* ws = (float4*)d_ws;                // 256 KB: (x,y,z,-||s||^2/2)
    (void)ws_size;

    prep<<<N_SRC / 512, 512, 0, stream>>>(src, ws, out);
    nn16<<<BLOCKS, TPB, 0, stream>>>(ws, src, tar, out);
}